// Round 2
// baseline (76.963 us; speedup 1.0000x reference)
//
#include <hip/hip_runtime.h>
#include <hip/hip_bf16.h>
#include <string.h>

// FourierKARTLayer: V[b,s,d] = sum_{q,k} A[d,q,k] * sin(k*(C_q + w_q*t_b) + Bp[d,q,k])
// v3 = verified v1 datapath + two low-risk levers (v2's 8-wave restructure failed
// correctness; reverted wholesale).
//   prep (736 blocks):
//     job0: W2[d, q*12+2(k-1)+{0,1}] = {A cosB, A sinB} bf16 interleaved  (v1-identical)
//     job1: Wc_w -> bf16 (Wcw)   [bit-identical RNE as v1's in-loop cvt]
//     job2: X0   -> bf16 (Xbf)   [bit-identical RNE as v1's in-loop cvt]
//   fused (512 blocks = 128 m-tiles x 4 d-QUARTERS, 256 threads = 4 waves):
//     - same wave q-chunk/K-chunk split as v1 (wave wv owns q [wv*32,+32) = K [wv*384,+384))
//     - GEMM1: 16 MFMA, pure bf16 loads (no cvt)  -> sincos -> wave-private LDS G slice
//     - __syncthreads (NEW, insurance: makes LDS G globally visible before GEMM2)
//     - GEMM2: 12 MFMA over own K-chunk, 16 d-outputs (nt loop removed)
//     - cross-wave 4-way K-reduce (v1 order) -> store
//   LDS 55296 B -> 2 blocks/CU -> 2 waves/SIMD (v1 had 1): latency hiding for the
//   serial chain, which is the bottleneck (both kernels are far off any throughput roof).
//   Output is bit-identical to v1 by construction => expect absmax 0.02148.

#define D_IN  256
#define D_OUT 64
#define NQ    128
#define NK    6
#define NB    2
#define NS    1024
#define NM    (NB*NS)      // 2048 rows
#define KJ    (NQ*NK*2)    // 1536
#define GSTR  392          // LDS G row stride in shorts (384 + 8 pad; 784 B = 49*16, b128-aligned)

typedef __attribute__((ext_vector_type(8))) short short8;   // 8 bf16 (MFMA A/B frag)
typedef __attribute__((ext_vector_type(4))) float floatx4;  // MFMA C/D frag

// workspace layout (in shorts): W2 [64*1536] | Wcw bf16 [128*256] | Xbf bf16 [2048*256]
#define W2_SOFF   0
#define WCW_SOFF  (D_OUT * KJ)              // 98304
#define XBF_SOFF  (WCW_SOFF + NQ * D_IN)    // 131072

__device__ inline unsigned short f2bf(float x) {
    __hip_bfloat16 h = __float2bfloat16(x);
    unsigned short u;
    memcpy(&u, &h, sizeof(u));
    return u;
}

__device__ inline unsigned int pack2bf(float lo, float hi) {
    return (unsigned int)f2bf(lo) | ((unsigned int)f2bf(hi) << 16);
}

// ---------------- prep: W2 + bf16 pre-conversion of Wc_w and X0 ----------------
// blocks [0,192): W2 (49152 elems, 1/thread)
// blocks [192,224): Wc_w fp32->bf16 (8192 float4s, 1/thread)
// blocks [224,736): X0  fp32->bf16 (131072 float4s, 1/thread)
__global__ __launch_bounds__(256) void prep_kernel(const float* __restrict__ A,
                                                   const float* __restrict__ Bp,
                                                   const float* __restrict__ Wc_w,
                                                   const float* __restrict__ X0,
                                                   unsigned short* __restrict__ ws) {
    const int bid = blockIdx.x;
    const int tid = threadIdx.x;
    if (bid < 192) {
        const int i = bid * 256 + tid;               // < 49152 exactly
        const int d = i / (NQ * NK);
        const int r = i % (NQ * NK);
        const int q = r / NK;
        const int k = r % NK;
        float s, c;
        __sincosf(Bp[i], &s, &c);
        const float a = A[i];
        unsigned short* W2 = ws + W2_SOFF;
        W2[(size_t)d * KJ + q * 12 + 2 * k]     = f2bf(a * c);  // pairs with sin(k theta)
        W2[(size_t)d * KJ + q * 12 + 2 * k + 1] = f2bf(a * s);  // pairs with cos(k theta)
    } else if (bid < 224) {
        const int i4 = (bid - 192) * 256 + tid;      // < 8192 exactly
        const float4 v = ((const float4*)Wc_w)[i4];
        ushort4 o;
        o.x = f2bf(v.x); o.y = f2bf(v.y); o.z = f2bf(v.z); o.w = f2bf(v.w);
        ((ushort4*)(ws + WCW_SOFF))[i4] = o;
    } else {
        const int i4 = (bid - 224) * 256 + tid;      // < 131072 exactly
        const float4 v = ((const float4*)X0)[i4];
        ushort4 o;
        o.x = f2bf(v.x); o.y = f2bf(v.y); o.z = f2bf(v.z); o.w = f2bf(v.w);
        ((ushort4*)(ws + XBF_SOFF))[i4] = o;
    }
}

// ---------------- fused: GEMM1 + sincos + GEMM2 ----------------
// grid: 512 blocks = 128 M-tiles x 4 D-quarters; 256 threads (4 waves).
__global__ __launch_bounds__(256) void fused_kernel(
        const unsigned short* __restrict__ ws,
        const float* __restrict__ Wc_b, const float* __restrict__ wq,
        const float* __restrict__ t, float* __restrict__ out) {
    const int m0   = (blockIdx.x >> 2) * 16;     // adjacent blocks share X rows (L2)
    const int d0   = (blockIdx.x & 3) * 16;
    const int wv   = threadIdx.x >> 6;           // wave 0..3: q-chunk = K-chunk owner
    const int lane = threadIdx.x & 63;
    const int lm   = lane & 15;
    const int quad = lane >> 4;

    __shared__ short Gl[4 * 16 * GSTR];          // 50176 B, wave-private 16x384 slices
    __shared__ float red[4][64][5];              // 5120 B, stride-5 = conflict-free

    const unsigned short* W2  = ws + W2_SOFF;
    const unsigned short* Wcw = ws + WCW_SOFF;
    const unsigned short* Xbf = ws + XBF_SOFF;

    // ---- GEMM1: theta[16 x 32q], q0 = wv*32, pure bf16 loads (no cvt) ----
    floatx4 acc1[2] = {floatx4{0,0,0,0}, floatx4{0,0,0,0}};
    const int q0 = wv * 32;
    const unsigned short* xrow = Xbf + (size_t)(m0 + lm) * D_IN + quad * 8;
#pragma unroll
    for (int k0 = 0; k0 < D_IN; k0 += 32) {
        short8 a = *(const short8*)(xrow + k0);
#pragma unroll
        for (int nt = 0; nt < 2; ++nt) {
            short8 b = *(const short8*)(Wcw + (size_t)(q0 + nt * 16 + lm) * D_IN
                                        + k0 + quad * 8);
            acc1[nt] = __builtin_amdgcn_mfma_f32_16x16x32_bf16(a, b, acc1[nt], 0, 0, 0);
        }
    }

    // ---- epilogue: sincos recurrence -> wave-private LDS G slice (v1 verbatim) ----
    const float tb = t[m0 / NS];                 // 16-row tile stays inside one batch
    short* gbase = Gl + wv * 16 * GSTR;
#pragma unroll
    for (int nt = 0; nt < 2; ++nt) {
        const int q = q0 + nt * 16 + lm;         // C/D: col = lane&15
        const float base = Wc_b[q] + wq[q] * tb;
#pragma unroll
        for (int r = 0; r < 4; ++r) {
            const int m = quad * 4 + r;          // C/D: row = quad*4 + reg (local)
            const float ang = acc1[nt][r] + base;
            float s1, c1;
            __sincosf(ang, &s1, &c1);
            unsigned int p[6];
            p[0] = pack2bf(s1, c1);
            float sk = s1, ck = c1;
#pragma unroll
            for (int k = 1; k < NK; ++k) {       // sin/cos(k*ang) by angle addition
                const float sn = sk * c1 + ck * s1;
                const float cn = ck * c1 - sk * s1;
                p[k] = pack2bf(sn, cn);
                sk = sn; ck = cn;
            }
            uint2* dst = reinterpret_cast<uint2*>(gbase + m * GSTR + (nt * 16 + lm) * 12);
            dst[0] = make_uint2(p[0], p[1]);
            dst[1] = make_uint2(p[2], p[3]);
            dst[2] = make_uint2(p[4], p[5]);
        }
    }
    __syncthreads();   // NEW (insurance): G slices globally visible before GEMM2 reads

    // ---- GEMM2: acc over K-chunk wv*384..+384, output 16m x 16d ----
    floatx4 acc2 = {0.f, 0.f, 0.f, 0.f};
    const short* gw = gbase + lm * GSTR + quad * 8;   // A[m=lm][k=quad*8+j] (local cols)
    const int j0 = wv * (KJ / 4);                     // 384
#pragma unroll
    for (int it = 0; it < KJ / 4 / 32; ++it) {   // 12 iters
        short8 a = *(const short8*)(gw + it * 32);
        short8 b = *(const short8*)((const short*)W2 + (size_t)(d0 + lm) * KJ
                                    + j0 + it * 32 + quad * 8);
        acc2 = __builtin_amdgcn_mfma_f32_16x16x32_bf16(a, b, acc2, 0, 0, 0);
    }

    // ---- cross-wave K-reduce (4-way, v1 summation order) + store ----
#pragma unroll
    for (int r = 0; r < 4; ++r)
        red[wv][lane][r] = acc2[r];
    __syncthreads();

    {
        const int r = wv;                        // thread (wv,lane) reduces reg r=wv
        const float v = red[0][lane][r] + red[1][lane][r]
                      + red[2][lane][r] + red[3][lane][r];
        out[(size_t)(m0 + quad * 4 + r) * D_OUT + d0 + lm] = v;
    }
}

extern "C" void kernel_launch(void* const* d_in, const int* in_sizes, int n_in,
                              void* d_out, int out_size, void* d_ws, size_t ws_size,
                              hipStream_t stream) {
    const float* X0   = (const float*)d_in[0];
    const float* t    = (const float*)d_in[1];
    const float* Wc_w = (const float*)d_in[2];
    const float* Wc_b = (const float*)d_in[3];
    const float* w    = (const float*)d_in[4];
    const float* A    = (const float*)d_in[5];
    const float* Bp   = (const float*)d_in[6];
    float* out = (float*)d_out;

    unsigned short* ws = (unsigned short*)d_ws;

    prep_kernel<<<736, 256, 0, stream>>>(A, Bp, Wc_w, X0, ws);
    fused_kernel<<<512, 256, 0, stream>>>(ws, Wc_b, w, t, out);
}